// Round 6
// baseline (95.468 us; speedup 1.0000x reference)
//
#include <hip/hip_runtime.h>
#include <hip/hip_bf16.h>

#define L_SEQ 65536
#define GROUPS_PER_B 256   // 4 tiles of 64 rows per block -> 256 rows/block

typedef __attribute__((ext_vector_type(8))) short bf16x8;
typedef __attribute__((ext_vector_type(4))) short s16x4;
typedef __attribute__((ext_vector_type(4))) float f32x4;

// workspace layout (bytes)
#define WS_WFX   0        // bf16 [3][64][64] : WfT_s[d][c] = (W_in@W_ip_x)^T[d][c] * conv_w[d][s]
#define WS_W1R   24576    // bf16 [64][64]    : W1rT[d][c]  (res half of in_proj, transposed)
#define WS_W2T   32768    // bf16 [64][64]    : W2T[c'][d] = (W_op@W_out)^T
#define WS_WG2T  40960    // bf16 [64][16]    : Wg2T[c][j] = W_g2[j][c]
#define WS_BX    43008    // f32 [64] : b1x*(w0+w1+w2) + conv_b   (interior conv bias)
#define WS_BR    43264    // f32 [64] : b1 res half
#define WS_BC0   43520    // f32 [64] : b1x*w0  (subtract at global row 0)
#define WS_BC2   43776    // f32 [64] : b1x*w2  (subtract at global row L-1)
#define WS_B2    44032    // f32 [64]

__device__ __forceinline__ short f2bf(float f) {
    __bf16 h = (__bf16)f;
    return __builtin_bit_cast(short, h);
}
__device__ __forceinline__ float fsigmoid(float x) {
    return __builtin_amdgcn_rcpf(1.0f + __builtin_amdgcn_exp2f(-1.44269504089f * x));
}

// ---------------- prep: compose + conv-fold weights ----------------
__global__ void prep_kernel(const float* __restrict__ W_in, const float* __restrict__ b_in,
                            const float* __restrict__ W_ip, const float* __restrict__ b_ip,
                            const float* __restrict__ conv_w, const float* __restrict__ conv_b,
                            const float* __restrict__ W_op, const float* __restrict__ b_op,
                            const float* __restrict__ W_g2,
                            const float* __restrict__ W_out, const float* __restrict__ b_out,
                            void* __restrict__ ws)
{
    short* wfx  = (short*)((char*)ws + WS_WFX);
    short* w1r  = (short*)((char*)ws + WS_W1R);
    short* w2t  = (short*)((char*)ws + WS_W2T);
    short* wg2t = (short*)((char*)ws + WS_WG2T);
    float* bx   = (float*)((char*)ws + WS_BX);
    float* br   = (float*)((char*)ws + WS_BR);
    float* bc0  = (float*)((char*)ws + WS_BC0);
    float* bc2  = (float*)((char*)ws + WS_BC2);
    float* b2   = (float*)((char*)ws + WS_B2);

    int tid = blockIdx.x * blockDim.x + threadIdx.x;
    if (tid < 12288) {                      // WfT_s[d][c], folded conv
        int s = tid >> 12, rem = tid & 4095;
        int d = rem >> 6, c = rem & 63;
        float acc = 0.f;
        for (int e = 0; e < 64; ++e) acc += W_in[c*64 + e] * W_ip[e*128 + d];
        wfx[(s*64 + d)*64 + c] = f2bf(acc * conv_w[3*d + s]);
    } else if (tid < 16384) {               // W1rT[d][c]
        int rem = tid - 12288; int d = rem >> 6, c = rem & 63;
        float acc = 0.f;
        for (int e = 0; e < 64; ++e) acc += W_in[c*64 + e] * W_ip[e*128 + 64 + d];
        w1r[d*64 + c] = f2bf(acc);
    } else if (tid < 20480) {               // W2T[c'][d]
        int rem = tid - 16384; int cp = rem >> 6, d = rem & 63;
        float acc = 0.f;
        for (int e = 0; e < 64; ++e) acc += W_op[d*64 + e] * W_out[e*64 + cp];
        w2t[cp*64 + d] = f2bf(acc);
    } else if (tid < 21504) {               // Wg2T[c][j]
        int rem = tid - 20480; int c = rem >> 4, j = rem & 15;
        wg2t[c*16 + j] = f2bf(W_g2[j*64 + c]);
    } else if (tid < 21568) {               // bx[d]
        int d = tid - 21504;
        float b1x = b_ip[d];
        for (int e = 0; e < 64; ++e) b1x += b_in[e] * W_ip[e*128 + d];
        bx[d] = b1x * (conv_w[3*d] + conv_w[3*d+1] + conv_w[3*d+2]) + conv_b[d];
    } else if (tid < 21632) {               // br[d]
        int d = tid - 21568;
        float s = b_ip[64 + d];
        for (int e = 0; e < 64; ++e) s += b_in[e] * W_ip[e*128 + 64 + d];
        br[d] = s;
    } else if (tid < 21696) {               // bc0[d]
        int d = tid - 21632;
        float b1x = b_ip[d];
        for (int e = 0; e < 64; ++e) b1x += b_in[e] * W_ip[e*128 + d];
        bc0[d] = b1x * conv_w[3*d];
    } else if (tid < 21760) {               // bc2[d]
        int d = tid - 21696;
        float b1x = b_ip[d];
        for (int e = 0; e < 64; ++e) b1x += b_in[e] * W_ip[e*128 + d];
        bc2[d] = b1x * conv_w[3*d + 2];
    } else if (tid < 21824) {               // b2[c']
        int cp = tid - 21760;
        float s = b_out[cp];
        for (int e = 0; e < 64; ++e) s += b_op[e] * W_out[e*64 + cp];
        b2[cp] = s;
    }
}

// ---------------- fused main kernel: 4 tiles/block, pipelined staging ----------------
// LDS = 2*8448 (xs) + 9216 (ot) + 2*2048 (hl) = 30208 B -> 5 blocks/CU by LDS
__global__ __launch_bounds__(256, 4) void fgs_main(
    const float* __restrict__ x, const float* __restrict__ freq,
    const float* __restrict__ wg1, const float* __restrict__ bg1,
    const float* __restrict__ bg2,
    const void* __restrict__ ws, float* __restrict__ out)
{
    const short* wfx  = (const short*)((const char*)ws + WS_WFX);
    const short* w1r  = (const short*)((const char*)ws + WS_W1R);
    const short* w2t  = (const short*)((const char*)ws + WS_W2T);
    const short* wg2t = (const short*)((const char*)ws + WS_WG2T);
    const float* bxv  = (const float*)((const char*)ws + WS_BX);
    const float* brv  = (const float*)((const char*)ws + WS_BR);
    const float* bc0  = (const float*)((const char*)ws + WS_BC0);
    const float* bc2  = (const float*)((const char*)ws + WS_BC2);
    const float* b2   = (const float*)((const char*)ws + WS_B2);

    // xs[b]: 66 rows x 64 bf16 (row i = tile base-1+i), 16B-chunk swizzle ^= (row&7)
    __shared__ short xs[2][66 * 64];
    __shared__ short ot[64][72];     // O = silu(conv_x)*silu(res)
    __shared__ short hl[2][64 * 16]; // H = relu(f*Wg1+bg1), double-buffered

    const int bid   = blockIdx.x;
    const int batch = bid >> 8;
    const int tg    = bid & 255;
    const int base0 = tg << 8;           // 256 rows per block

    const int lane = threadIdx.x & 63;
    const int w    = threadIdx.x >> 6;
    const int lr   = lane & 15;
    const int g    = lane >> 4;
    const int r    = 16*w + lr;
    const int c0   = 16*w + 4*g;

    const size_t brow0 = (size_t)batch * L_SEQ;

    // ---- persistent A-fragments (loaded once per block) ----
    bf16x8 awf[2][3], awr[2];
    #pragma unroll
    for (int kk = 0; kk < 2; ++kk) {
        #pragma unroll
        for (int s = 0; s < 3; ++s)
            awf[kk][s] = *(const bf16x8*)(wfx + (s*64 + 16*w + lr)*64 + 32*kk + 8*g);
        awr[kk] = *(const bf16x8*)(w1r + (16*w + lr)*64 + 32*kk + 8*g);
    }
    const float4 bbx = *(const float4*)(bxv + c0);
    const float4 bbr = *(const float4*)(brv + c0);
    const float4 wgv = *(const float4*)(wg1 + 4*g);
    const float4 bgv = *(const float4*)(bg1 + 4*g);

    // ---- stage machinery: issue-early / write-late (T14) ----
    float4 sa, sb, sc, sd; float sf;
    const int sro = threadIdx.x >> 2;        // staged row 0..63 (LDS row 2+sro)
    const int sq  = (threadIdx.x & 3) * 16;  // f32 col base

    auto stage_issue = [&](int tb) {         // tb = staged tile's base
        int grow = tb + 1 + sro;             // rows tb+1 .. tb+64
        bool v = ((unsigned)grow < (unsigned)L_SEQ);
        const float* p = x + (brow0 + (size_t)(v ? grow : 0)) * 64 + sq;
        sa = *(const float4*)(p);
        sb = *(const float4*)(p + 4);
        sc = *(const float4*)(p + 8);
        sd = *(const float4*)(p + 12);
        sf = freq[brow0 + tb + r];           // always in range
    };
    auto stage_write = [&](short* xb, int tb) {
        int i = 2 + sro;
        int grow = tb + 1 + sro;
        bool v = ((unsigned)grow < (unsigned)L_SEQ);
        bf16x8 lo, hi;
        lo[0]=f2bf(sa.x); lo[1]=f2bf(sa.y); lo[2]=f2bf(sa.z); lo[3]=f2bf(sa.w);
        lo[4]=f2bf(sb.x); lo[5]=f2bf(sb.y); lo[6]=f2bf(sb.z); lo[7]=f2bf(sb.w);
        hi[0]=f2bf(sc.x); hi[1]=f2bf(sc.y); hi[2]=f2bf(sc.z); hi[3]=f2bf(sc.w);
        hi[4]=f2bf(sd.x); hi[5]=f2bf(sd.y); hi[6]=f2bf(sd.z); hi[7]=f2bf(sd.w);
        if (!v) { bf16x8 z = {}; lo = z; hi = z; }
        int cb = sq >> 3;
        int sw = i & 7;
        *(bf16x8*)&xb[i*64 + ((cb    ) ^ sw) * 8] = lo;
        *(bf16x8*)&xb[i*64 + ((cb + 1) ^ sw) * 8] = hi;
    };
    auto halo_copy = [&](short* xb, const short* xprev) {
        // next tile rows i=0,1 == prev tile rows i=64,65; (64+ii)&7 == ii&7 -> raw copy
        if (threadIdx.x < 16) {
            int ii = threadIdx.x >> 3;
            int cc = threadIdx.x & 7;
            *(bf16x8*)&xb[ii*64 + cc*8] = *(const bf16x8*)&xprev[(64 + ii)*64 + cc*8];
        }
    };
    auto hl_write = [&](short* hb) {
        s16x4 hv;
        hv[0] = f2bf(fmaxf(sf*wgv.x + bgv.x, 0.f));
        hv[1] = f2bf(fmaxf(sf*wgv.y + bgv.y, 0.f));
        hv[2] = f2bf(fmaxf(sf*wgv.z + bgv.z, 0.f));
        hv[3] = f2bf(fmaxf(sf*wgv.w + bgv.w, 0.f));
        *(s16x4*)&hb[r*16 + 4*g] = hv;
    };

    // ---- prologue: stage tile 0 (incl. halo rows 0,1), hl[0] ----
    stage_issue(base0);
    if (threadIdx.x < 8) {                   // rows i=0,1 (global base0-1, base0)
        int i = threadIdx.x >> 2;
        int grow = base0 - 1 + i;
        bool v = (grow >= 0);
        const float* p = x + (brow0 + (size_t)(v ? grow : 0)) * 64 + sq;
        float4 a = *(const float4*)(p);
        float4 b = *(const float4*)(p + 4);
        float4 c = *(const float4*)(p + 8);
        float4 d = *(const float4*)(p + 12);
        bf16x8 lo, hi;
        lo[0]=f2bf(a.x); lo[1]=f2bf(a.y); lo[2]=f2bf(a.z); lo[3]=f2bf(a.w);
        lo[4]=f2bf(b.x); lo[5]=f2bf(b.y); lo[6]=f2bf(b.z); lo[7]=f2bf(b.w);
        hi[0]=f2bf(c.x); hi[1]=f2bf(c.y); hi[2]=f2bf(c.z); hi[3]=f2bf(c.w);
        hi[4]=f2bf(d.x); hi[5]=f2bf(d.y); hi[6]=f2bf(d.z); hi[7]=f2bf(d.w);
        if (!v) { bf16x8 z = {}; lo = z; hi = z; }
        int cb = sq >> 3;
        int sw = i & 7;
        *(bf16x8*)&xs[0][i*64 + ((cb    ) ^ sw) * 8] = lo;
        *(bf16x8*)&xs[0][i*64 + ((cb + 1) ^ sw) * 8] = hi;
    }
    stage_write(xs[0], base0);
    hl_write(hl[0]);
    __syncthreads();                         // A(0)

    // ---- 4-tile pipelined main loop ----
    #pragma unroll
    for (int t = 0; t < 4; ++t) {
        const int tb = base0 + (t << 6);
        short* xcur = xs[t & 1];
        short* xnxt = xs[(t & 1) ^ 1];
        short* hcur = hl[t & 1];
        short* hnxt = hl[(t & 1) ^ 1];

        if (t < 3) stage_issue(tb + 64);     // issue next tile's loads (hide under GEMM1+GEMM2)

        // GEMM1 (conv-folded): accx = conv(x@W1x), accr = x@W1r
        f32x4 accx[4] = {};
        f32x4 accr[4] = {};
        #pragma unroll
        for (int kk = 0; kk < 2; ++kk) {
            #pragma unroll
            for (int s = 0; s < 3; ++s) {
                int rb = lr + s;
                const short* bp = xcur + rb*64 + (((4*kk + g) ^ (rb & 7)) * 8);
                bf16x8 b0 = *(const bf16x8*)(bp);
                bf16x8 b1v = *(const bf16x8*)(bp + 1024);
                bf16x8 b2v = *(const bf16x8*)(bp + 2048);
                bf16x8 b3v = *(const bf16x8*)(bp + 3072);
                accx[0] = __builtin_amdgcn_mfma_f32_16x16x32_bf16(awf[kk][s], b0,  accx[0], 0, 0, 0);
                accx[1] = __builtin_amdgcn_mfma_f32_16x16x32_bf16(awf[kk][s], b1v, accx[1], 0, 0, 0);
                accx[2] = __builtin_amdgcn_mfma_f32_16x16x32_bf16(awf[kk][s], b2v, accx[2], 0, 0, 0);
                accx[3] = __builtin_amdgcn_mfma_f32_16x16x32_bf16(awf[kk][s], b3v, accx[3], 0, 0, 0);
                if (s == 1) {
                    accr[0] = __builtin_amdgcn_mfma_f32_16x16x32_bf16(awr[kk], b0,  accr[0], 0, 0, 0);
                    accr[1] = __builtin_amdgcn_mfma_f32_16x16x32_bf16(awr[kk], b1v, accr[1], 0, 0, 0);
                    accr[2] = __builtin_amdgcn_mfma_f32_16x16x32_bf16(awr[kk], b2v, accr[2], 0, 0, 0);
                    accr[3] = __builtin_amdgcn_mfma_f32_16x16x32_bf16(awr[kk], b3v, accr[3], 0, 0, 0);
                }
            }
        }

        // epilogue 1: o = silu(x_conv)*silu(res) -> ot
        #pragma unroll
        for (int nt = 0; nt < 4; ++nt) {
            int trow = 16*nt + lr;
            f32x4 vx = accx[nt];
            f32x4 vr = accr[nt];
            vx[0] += bbx.x; vx[1] += bbx.y; vx[2] += bbx.z; vx[3] += bbx.w;
            vr[0] += bbr.x; vr[1] += bbr.y; vr[2] += bbr.z; vr[3] += bbr.w;
            if (t == 0 && nt == 0 && tg == 0 && lr == 0) {          // global row 0
                float4 cc = *(const float4*)(bc0 + c0);
                vx[0] -= cc.x; vx[1] -= cc.y; vx[2] -= cc.z; vx[3] -= cc.w;
            }
            if (t == 3 && nt == 3 && tg == 255 && lr == 15) {       // global row L-1
                float4 cc = *(const float4*)(bc2 + c0);
                vx[0] -= cc.x; vx[1] -= cc.y; vx[2] -= cc.z; vx[3] -= cc.w;
            }
            s16x4 pv;
            #pragma unroll
            for (int j = 0; j < 4; ++j) {
                float xx = vx[j], rr = vr[j];
                float ex = __builtin_amdgcn_exp2f(-1.44269504089f * xx);
                float er = __builtin_amdgcn_exp2f(-1.44269504089f * rr);
                float o = xx * rr * __builtin_amdgcn_rcpf((1.0f + ex) * (1.0f + er));
                pv[j] = f2bf(o);
            }
            *(s16x4*)&ot[trow][c0] = pv;
        }
        __syncthreads();                     // B(t)

        // write-late: next tile's xs + hl land here, hidden under GEMM2
        if (t < 3) {
            stage_write(xnxt, tb + 64);
            halo_copy(xnxt, xcur);
            hl_write(hnxt);
        }

        // GEMM2: Y^T = W2T @ O^T ; gate: Wg2T @ H^T
        bf16x8 a2_0 = *(const bf16x8*)(w2t + (16*w + lr)*64 + 8*g);
        bf16x8 a2_1 = *(const bf16x8*)(w2t + (16*w + lr)*64 + 32 + 8*g);
        bf16x8 zf = {};
        bf16x8 ag = (g < 2) ? *(const bf16x8*)(wg2t + (16*w + lr)*16 + 8*g) : zf;
        f32x4 acc2[4] = {};
        f32x4 accg[4] = {};
        #pragma unroll
        for (int nt = 0; nt < 4; ++nt) {
            int row = 16*nt + lr;
            bf16x8 bo0 = *(bf16x8*)&ot[row][8*g];
            bf16x8 bo1 = *(bf16x8*)&ot[row][32 + 8*g];
            bf16x8 bh  = (g < 2) ? *(bf16x8*)&hcur[row*16 + 8*g] : zf;
            acc2[nt] = __builtin_amdgcn_mfma_f32_16x16x32_bf16(a2_0, bo0, acc2[nt], 0, 0, 0);
            acc2[nt] = __builtin_amdgcn_mfma_f32_16x16x32_bf16(a2_1, bo1, acc2[nt], 0, 0, 0);
            accg[nt] = __builtin_amdgcn_mfma_f32_16x16x32_bf16(ag,   bh,  accg[nt], 0, 0, 0);
        }

        // epilogue 2: y = (Y + b2) * sigmoid(G + bg2)
        {
            float4 bb2 = *(const float4*)(b2 + c0);
            float4 bbg = *(const float4*)(bg2 + c0);
            float* op0 = out + (brow0 + (size_t)(tb + lr)) * 64 + c0;
            #pragma unroll
            for (int nt = 0; nt < 4; ++nt) {
                f32x4 y = acc2[nt], gg = accg[nt];
                float4 o;
                o.x = (y[0] + bb2.x) * fsigmoid(gg[0] + bbg.x);
                o.y = (y[1] + bb2.y) * fsigmoid(gg[1] + bbg.y);
                o.z = (y[2] + bb2.z) * fsigmoid(gg[2] + bbg.z);
                o.w = (y[3] + bb2.w) * fsigmoid(gg[3] + bbg.w);
                *(float4*)(op0 + (size_t)(nt << 4) * 64) = o;
            }
        }
        if (t < 3) __syncthreads();          // A(t+1)
    }
}

extern "C" void kernel_launch(void* const* d_in, const int* in_sizes, int n_in,
                              void* d_out, int out_size, void* d_ws, size_t ws_size,
                              hipStream_t stream)
{
    const float* x      = (const float*)d_in[0];
    const float* freq   = (const float*)d_in[1];
    const float* W_in   = (const float*)d_in[2];
    const float* b_in   = (const float*)d_in[3];
    const float* W_ip   = (const float*)d_in[4];
    const float* b_ip   = (const float*)d_in[5];
    const float* conv_w = (const float*)d_in[6];
    const float* conv_b = (const float*)d_in[7];
    const float* W_op   = (const float*)d_in[8];
    const float* b_op   = (const float*)d_in[9];
    const float* W_g1   = (const float*)d_in[10];
    const float* b_g1   = (const float*)d_in[11];
    const float* W_g2   = (const float*)d_in[12];
    const float* b_g2   = (const float*)d_in[13];
    const float* W_out  = (const float*)d_in[14];
    const float* b_out  = (const float*)d_in[15];
    float* out = (float*)d_out;

    prep_kernel<<<86, 256, 0, stream>>>(W_in, b_in, W_ip, b_ip, conv_w, conv_b,
                                        W_op, b_op, W_g2, W_out, b_out, d_ws);
    fgs_main<<<8 * GROUPS_PER_B, 256, 0, stream>>>(x, freq, W_g1, b_g1, b_g2, d_ws, out);
}